// Round 7
// baseline (281.035 us; speedup 1.0000x reference)
//
#include <hip/hip_runtime.h>
#include <hip/hip_bf16.h>

#define D_MODEL 1024
#define L_SEQ   2048
#define BATCH   2
#define NROWS   (BATCH*L_SEQ)   // 4096
#define N_HEADS 16
#define HD      64
#define WIN     128             // half window

typedef __attribute__((ext_vector_type(8))) short short8;
typedef __attribute__((ext_vector_type(4))) float f32x4;
typedef __attribute__((ext_vector_type(4))) int   i32x4;
typedef __attribute__((ext_vector_type(4))) unsigned short u16x4;

__device__ __forceinline__ float bf2f(unsigned short u) {
  union { unsigned int i; float f; } c;
  c.i = ((unsigned int)u) << 16;
  return c.f;
}
__device__ __forceinline__ unsigned short f2bf(float f) {
  __hip_bfloat16 h = __float2bfloat16(f);
  return *reinterpret_cast<unsigned short*>(&h);
}

// async global->LDS, 16B per lane. LDS dest is wave-uniform base + lane*16.
__device__ __forceinline__ void gload16(const void* g, void* l) {
  __builtin_amdgcn_global_load_lds((const __attribute__((address_space(1))) unsigned int*)g,
                                   (__attribute__((address_space(3))) unsigned int*)l, 16, 0, 0);
}

// ---------------- prep: 4 weight transposes (f32 [K][N] -> bf16 [N][K]) + LN1 ----------------
__device__ __forceinline__ void wtrans_body(const float* __restrict__ W,
                                            __hip_bfloat16* __restrict__ Wt,
                                            int K, int N, int tile_id) {
  __shared__ float tile[32][33];
  int tx = threadIdx.x & 31, ty = threadIdx.x >> 5;   // 32 x 8
  int ntile_n = N >> 5;
  int n0 = (tile_id % ntile_n) * 32, k0 = (tile_id / ntile_n) * 32;
#pragma unroll
  for (int i = 0; i < 4; ++i) {
    int k = k0 + ty + i * 8;
    tile[ty + i * 8][tx] = W[(size_t)k * N + n0 + tx];
  }
  __syncthreads();
#pragma unroll
  for (int i = 0; i < 4; ++i) {
    int n = n0 + ty + i * 8;
    Wt[(size_t)n * K + k0 + tx] = __float2bfloat16(tile[tx][ty + i * 8]);
  }
}

__device__ __forceinline__ void ln_body(const float* __restrict__ x,
                                        const float* __restrict__ g,
                                        const float* __restrict__ beta,
                                        __hip_bfloat16* __restrict__ out, int row) {
  int t = threadIdx.x;
  const float4* xr = (const float4*)(x + (size_t)row * D_MODEL);
  float4 v = xr[t];
  float s  = v.x + v.y + v.z + v.w;
  float sq = v.x * v.x + v.y * v.y + v.z * v.z + v.w * v.w;
#pragma unroll
  for (int off = 32; off; off >>= 1) {
    s  += __shfl_xor(s, off);
    sq += __shfl_xor(sq, off);
  }
  __shared__ float red[8];
  int w = t >> 6;
  if ((t & 63) == 0) { red[w] = s; red[4 + w] = sq; }
  __syncthreads();
  s  = red[0] + red[1] + red[2] + red[3];
  sq = red[4] + red[5] + red[6] + red[7];
  float mean = s * (1.0f / 1024.0f);
  float var  = sq * (1.0f / 1024.0f) - mean * mean;
  float rs   = rsqrtf(var + 1e-5f);
  float4 gv = ((const float4*)g)[t];
  float4 bv = ((const float4*)beta)[t];
  u16x4 o;
  o.x = f2bf((v.x - mean) * rs * gv.x + bv.x);
  o.y = f2bf((v.y - mean) * rs * gv.y + bv.y);
  o.z = f2bf((v.z - mean) * rs * gv.z + bv.z);
  o.w = f2bf((v.w - mean) * rs * gv.w + bv.w);
  ((u16x4*)(out + (size_t)row * D_MODEL))[t] = o;
}

__global__ __launch_bounds__(256) void prep_kernel(
    const float* __restrict__ qkv_w, __hip_bfloat16* __restrict__ wqkvT,
    const float* __restrict__ out_w, __hip_bfloat16* __restrict__ woutT,
    const float* __restrict__ ffn_w1, __hip_bfloat16* __restrict__ wf1T,
    const float* __restrict__ ffn_w2, __hip_bfloat16* __restrict__ wf2T,
    const float* __restrict__ x, const float* __restrict__ ln1_g,
    const float* __restrict__ ln1_b, __hip_bfloat16* __restrict__ hbuf) {
  int id = blockIdx.x;
  if (id < 3072)      wtrans_body(qkv_w,  wqkvT, 1024, 3072, id);
  else if (id < 4096) wtrans_body(out_w,  woutT, 1024, 1024, id - 3072);
  else if (id < 6144) wtrans_body(ffn_w1, wf1T,  1024, 2048, id - 4096);
  else if (id < 8192) wtrans_body(ffn_w2, wf2T,  2048, 1024, id - 6144);
  else                ln_body(x, ln1_g, ln1_b, hbuf, id - 8192);
}

// ---------------- standalone layernorm (for LN2) ----------------
__global__ __launch_bounds__(256) void ln_kernel(const float* __restrict__ x,
                                                 const float* __restrict__ g,
                                                 const float* __restrict__ beta,
                                                 __hip_bfloat16* __restrict__ out) {
  ln_body(x, g, beta, out, blockIdx.x);
}

// ---------------- V transpose: qkv V part -> vT[bh][d][j] bf16 ----------------
__global__ __launch_bounds__(256) void vtrans_kernel(const __hip_bfloat16* __restrict__ qkv,
                                                     __hip_bfloat16* __restrict__ vT) {
  __shared__ unsigned short tile[64][72];
  int bh = blockIdx.y, b = bh >> 4, h = bh & 15;
  int j0 = blockIdx.x * 64;
  int t = threadIdx.x;
#pragma unroll
  for (int i = 0; i < 2; ++i) {
    int c = t + i * 256;            // 0..511
    int row = c >> 3, off = c & 7;  // row 0..63, 16B chunk
    *(i32x4*)&tile[row][off * 8] =
        *(const i32x4*)&qkv[(size_t)(b * L_SEQ + j0 + row) * 3072 + 2 * D_MODEL + h * 64 + off * 8];
  }
  __syncthreads();
#pragma unroll
  for (int i = 0; i < 2; ++i) {
    int c = t + i * 256;
    int d = c >> 3, off = c & 7;    // d 0..63, j chunk
    short8 o;
#pragma unroll
    for (int e = 0; e < 8; ++e) o[e] = (short)tile[off * 8 + e][d];
    *(short8*)&vT[((size_t)bh * 64 + d) * 2048 + j0 + off * 8] = o;
  }
}

// ---------------- 256x256 MFMA GEMM: 2-phase dbuf, gload_lds + pre-swizzled src ----------------
// 512 threads, 8 waves (2M x 4N), each wave owns 128x64. LDS 128 KB dynamic.
// Intensity 128 FLOP/B staged (2x the 128-tile) -> staging-BW ceiling doubled.
// MODE 0: bias -> bf16 ; MODE 1: gelu(bias+acc) -> bf16
template <int MODE>
__global__ __launch_bounds__(512, 1) void gemm256_kernel(const __hip_bfloat16* __restrict__ A,
                                                         const __hip_bfloat16* __restrict__ Bt,
                                                         const float* __restrict__ bias,
                                                         void* __restrict__ outp,
                                                         int M, int N, int K) {
  (void)M;
  extern __shared__ __align__(16) char lds[];   // [buf][A 32K | B 32K]

  int tid  = threadIdx.x;
  int lane = tid & 63;
  int wave = tid >> 6;          // 0..7
  int wr = wave >> 2, wc = wave & 3;
  int l15 = lane & 15, lg = lane >> 4;

  // XCD-chunked bijective swizzle (grids are multiples of 8)
  int gx = gridDim.x;
  int nwg = gx * gridDim.y;
  int flat = blockIdx.y * gx + blockIdx.x;
  int cpx = nwg >> 3;
  int sw = (flat & 7) * cpx + (flat >> 3);
  int m0 = (sw / gx) * 256;
  int n0 = (sw % gx) * 256;

  const char* Abase = (const char*)A;
  const char* Bbase = (const char*)Bt;
  size_t strideK = (size_t)K * 2;
  int KT = K >> 6;

  int srow_in = lane >> 3;                      // 0..7 == row&7
  int scb_src = ((lane & 7) ^ srow_in) * 16;    // pre-swizzled global byte col

  auto STAGE = [&](int buf, int kt) {
    size_t kb = (size_t)kt * 128;
    char* lA = lds + buf * 65536;
    char* lB = lds + buf * 65536 + 32768;
#pragma unroll
    for (int i = 0; i < 4; ++i) {
      int chunk = wave * 4 + i;            // 0..31, wave-uniform
      int row = chunk * 8 + srow_in;       // 0..255
      gload16(Abase + (size_t)(m0 + row) * strideK + kb + scb_src, lA + chunk * 1024);
      gload16(Bbase + (size_t)(n0 + row) * strideK + kb + scb_src, lB + chunk * 1024);
    }
  };

  f32x4 acc[8][4];
#pragma unroll
  for (int i = 0; i < 8; ++i)
#pragma unroll
    for (int j = 0; j < 4; ++j) acc[i][j] = (f32x4){0.f, 0.f, 0.f, 0.f};

  STAGE(0, 0);
  __syncthreads();

  for (int kt = 0; kt < KT; ++kt) {
    int cur = kt & 1;
    if (kt + 1 < KT) STAGE(cur ^ 1, kt + 1);
    const char* lA = lds + cur * 65536;
    const char* lB = lds + cur * 65536 + 32768;
#pragma unroll
    for (int ks = 0; ks < 2; ++ks) {
      short8 bfr[4];
#pragma unroll
      for (int ni = 0; ni < 4; ++ni) {
        int row = wc * 64 + ni * 16 + l15;
        bfr[ni] = *(const short8*)(lB + row * 128 + ((ks * 64 + lg * 16) ^ ((row & 7) << 4)));
      }
#pragma unroll
      for (int mi = 0; mi < 8; ++mi) {
        int row = wr * 128 + mi * 16 + l15;
        short8 af = *(const short8*)(lA + row * 128 + ((ks * 64 + lg * 16) ^ ((row & 7) << 4)));
#pragma unroll
        for (int ni = 0; ni < 4; ++ni)
          acc[mi][ni] = __builtin_amdgcn_mfma_f32_16x16x32_bf16(af, bfr[ni], acc[mi][ni], 0, 0, 0);
      }
    }
    __syncthreads();
  }

  int colg = n0 + wc * 64;
  int rowg = m0 + wr * 128;
#pragma unroll
  for (int mi = 0; mi < 8; ++mi) {
#pragma unroll
    for (int ni = 0; ni < 4; ++ni) {
      int col = colg + ni * 16 + l15;
      float bs = bias[col];
#pragma unroll
      for (int r = 0; r < 4; ++r) {
        int row = rowg + mi * 16 + (lg << 2) + r;
        float v = acc[mi][ni][r] + bs;
        if (MODE == 1) v = 0.5f * v * (1.0f + erff(v * 0.70710678118654752f));
        ((__hip_bfloat16*)outp)[(size_t)row * N + col] = __float2bfloat16(v);
      }
    }
  }
}

// ---------------- 128x128 MFMA GEMM (kept for N=1024 shapes) ----------------
// MODE 2: bias+acc+resid -> f32
template <int MODE>
__global__ __launch_bounds__(256) void gemm_kernel(const __hip_bfloat16* __restrict__ A,
                                                   const __hip_bfloat16* __restrict__ Bt,
                                                   const float* __restrict__ bias,
                                                   const float* __restrict__ resid,
                                                   void* __restrict__ outp,
                                                   int M, int N, int K) {
  (void)M;
  __shared__ __align__(16) char lsA[2][128 * 128];
  __shared__ __align__(16) char lsB[2][128 * 128];

  int tid  = threadIdx.x;
  int lane = tid & 63;
  int wave = tid >> 6;
  int wr = wave >> 1, wc = wave & 1;
  int l15 = lane & 15, lg = lane >> 4;

  int gx = gridDim.x;
  int nwg = gx * gridDim.y;
  int flat = blockIdx.y * gx + blockIdx.x;
  int cpx = nwg >> 3;
  int sw = (flat & 7) * cpx + (flat >> 3);
  int m0 = (sw / gx) * 128;
  int n0 = (sw % gx) * 128;

  const char* Abase = (const char*)A;
  const char* Bbase = (const char*)Bt;
  size_t strideK = (size_t)K * 2;
  int KT = K >> 6;

  int srow_in  = lane >> 3;
  int scb_src  = (((lane & 7) ^ srow_in)) * 16;

  auto STAGE = [&](int buf, int kt) {
    size_t kb = (size_t)kt * 128;
#pragma unroll
    for (int i = 0; i < 4; ++i) {
      int chunk = wave * 4 + i;
      int row = chunk * 8 + srow_in;
      gload16(Abase + (size_t)(m0 + row) * strideK + kb + scb_src, lsA[buf] + chunk * 1024);
      gload16(Bbase + (size_t)(n0 + row) * strideK + kb + scb_src, lsB[buf] + chunk * 1024);
    }
  };

  f32x4 acc[4][4];
#pragma unroll
  for (int i = 0; i < 4; ++i)
#pragma unroll
    for (int j = 0; j < 4; ++j) acc[i][j] = (f32x4){0.f, 0.f, 0.f, 0.f};

  STAGE(0, 0);
  __syncthreads();

  for (int kt = 0; kt < KT; ++kt) {
    int cur = kt & 1;
    if (kt + 1 < KT) STAGE(cur ^ 1, kt + 1);
#pragma unroll
    for (int ks = 0; ks < 2; ++ks) {
      short8 af[4], bfr[4];
#pragma unroll
      for (int mi = 0; mi < 4; ++mi) {
        int row = wr * 64 + mi * 16 + l15;
        af[mi] = *(const short8*)(lsA[cur] + row * 128 + ((ks * 64 + lg * 16) ^ ((row & 7) << 4)));
      }
#pragma unroll
      for (int ni = 0; ni < 4; ++ni) {
        int row = wc * 64 + ni * 16 + l15;
        bfr[ni] = *(const short8*)(lsB[cur] + row * 128 + ((ks * 64 + lg * 16) ^ ((row & 7) << 4)));
      }
#pragma unroll
      for (int mi = 0; mi < 4; ++mi)
#pragma unroll
        for (int ni = 0; ni < 4; ++ni)
          acc[mi][ni] = __builtin_amdgcn_mfma_f32_16x16x32_bf16(af[mi], bfr[ni], acc[mi][ni], 0, 0, 0);
    }
    __syncthreads();
  }

  int colg = n0 + wc * 64;
  int rowg = m0 + wr * 64;
#pragma unroll
  for (int mi = 0; mi < 4; ++mi) {
#pragma unroll
    for (int ni = 0; ni < 4; ++ni) {
      int col = colg + ni * 16 + l15;
      float bs = bias[col];
#pragma unroll
      for (int r = 0; r < 4; ++r) {
        int row = rowg + mi * 16 + (lg << 2) + r;
        float v = acc[mi][ni][r] + bs;
        if (MODE == 1) v = 0.5f * v * (1.0f + erff(v * 0.70710678118654752f));
        if (MODE == 2) {
          ((float*)outp)[(size_t)row * N + col] = v + resid[(size_t)row * N + col];
        } else {
          ((__hip_bfloat16*)outp)[(size_t)row * N + col] = __float2bfloat16(v);
        }
      }
    }
  }
}

// ---------------- MFMA windowed attention ----------------
// Block: 64 q-rows of one (b,h); 4 waves x 16 q-rows. 5 key chunks of 64 (=320 keys).
__global__ __launch_bounds__(256) void attn_mfma_kernel(const __hip_bfloat16* __restrict__ qkv,
                                                        const __hip_bfloat16* __restrict__ vT,
                                                        __hip_bfloat16* __restrict__ out) {
  __shared__ char Ks[2][8192];   // 64 keys x 128B (swizzled)
  __shared__ char Vs[2][8192];   // 64 d    x 128B of j (swizzled)
  __shared__ char Ps[4][2304];   // per-wave P chunk: 16 x 72 bf16

  const int t = threadIdx.x;
  const int lane = t & 63;
  const int wave = t >> 6;
  const int l15 = lane & 15;
  const int lg  = lane >> 4;
  const int bh = blockIdx.y, b = bh >> 4, h = bh & 15;
  const int q0 = blockIdx.x * 64;
  const int jlo = q0 - 128;

  short8 qf0, qf1;
  {
    int qrow = q0 + wave * 16 + l15;
    const char* qp = (const char*)qkv + 2 * ((size_t)(b * L_SEQ + qrow) * 3072 + h * 64 + 8 * lg);
    qf0 = *(const short8*)qp;
    qf1 = *(const short8*)(qp + 64);
  }

  const int srow = t >> 3;           // 0..31 (two rows per thread: srow, srow+32)
  const int soff = (t & 7) * 16;     // byte chunk in 128B row
  const int jel  = (t & 7) * 8;      // element offset (j)

  const char* kgbase = (const char*)qkv + 2 * ((size_t)b * L_SEQ * 3072 + D_MODEL + h * 64);
  const char* vgbase = (const char*)vT + 2 * ((size_t)bh * 64 * 2048);

  f32x4 sc[5][4];
#pragma unroll
  for (int c = 0; c < 5; ++c)
#pragma unroll
    for (int tt = 0; tt < 4; ++tt) sc[c][tt] = (f32x4){0.f, 0.f, 0.f, 0.f};

  // ---- pass 1: QK^T ----
  {
    i32x4 kr[2];
#pragma unroll
    for (int i = 0; i < 2; ++i) {
      int rr = srow + i * 32;
      int tok = jlo + rr; tok = tok < 0 ? 0 : (tok > 2047 ? 2047 : tok);
      kr[i] = *(const i32x4*)(kgbase + (size_t)tok * 6144 + soff);
    }
#pragma unroll
    for (int i = 0; i < 2; ++i) {
      int rr = srow + i * 32;
      *(i32x4*)(Ks[0] + rr * 128 + (soff ^ ((rr & 7) << 4))) = kr[i];
    }
  }
  __syncthreads();

#pragma unroll
  for (int c = 0; c < 5; ++c) {
    int cur = c & 1;
    i32x4 nk[2];
    if (c < 4) {
#pragma unroll
      for (int i = 0; i < 2; ++i) {
        int rr = srow + i * 32;
        int tok = jlo + (c + 1) * 64 + rr; tok = tok < 0 ? 0 : (tok > 2047 ? 2047 : tok);
        nk[i] = *(const i32x4*)(kgbase + (size_t)tok * 6144 + soff);
      }
    }
#pragma unroll
    for (int tt = 0; tt < 4; ++tt) {
      int row = tt * 16 + l15;
      short8 k0 = *(const short8*)(Ks[cur] + row * 128 + ((lg * 16) ^ ((row & 7) << 4)));
      short8 k1 = *(const short8*)(Ks[cur] + row * 128 + ((64 + lg * 16) ^ ((row & 7) << 4)));
      sc[c][tt] = __builtin_amdgcn_mfma_f32_16x16x32_bf16(qf0, k0, sc[c][tt], 0, 0, 0);
      sc[c][tt] = __builtin_amdgcn_mfma_f32_16x16x32_bf16(qf1, k1, sc[c][tt], 0, 0, 0);
    }
    if (c < 4) {
      __syncthreads();
#pragma unroll
      for (int i = 0; i < 2; ++i) {
        int rr = srow + i * 32;
        *(i32x4*)(Ks[cur ^ 1] + rr * 128 + (soff ^ ((rr & 7) << 4))) = nk[i];
      }
      __syncthreads();
    }
  }

  // ---- mask + softmax ----
  const int iqb = q0 + wave * 16 + 4 * lg;
  const int kgb = jlo + l15;
#pragma unroll
  for (int c = 0; c < 5; ++c)
#pragma unroll
    for (int tt = 0; tt < 4; ++tt) {
      int kg = kgb + c * 64 + tt * 16;
#pragma unroll
      for (int r = 0; r < 4; ++r) {
        int iq = iqb + r;
        bool ok = (kg >= 0) && (kg < L_SEQ) && (kg >= iq - WIN) && (kg <= iq + WIN);
        sc[c][tt][r] = ok ? sc[c][tt][r] * 0.125f : -1e30f;
      }
    }
  float mx[4] = {-1e30f, -1e30f, -1e30f, -1e30f};
#pragma unroll
  for (int c = 0; c < 5; ++c)
#pragma unroll
    for (int tt = 0; tt < 4; ++tt)
#pragma unroll
      for (int r = 0; r < 4; ++r) mx[r] = fmaxf(mx[r], sc[c][tt][r]);
#pragma unroll
  for (int r = 0; r < 4; ++r)
#pragma unroll
    for (int off = 8; off; off >>= 1) mx[r] = fmaxf(mx[r], __shfl_xor(mx[r], off, 16));
  float sm[4] = {0.f, 0.f, 0.f, 0.f};
#pragma unroll
  for (int c = 0; c < 5; ++c)
#pragma unroll
    for (int tt = 0; tt < 4; ++tt)
#pragma unroll
      for (int r = 0; r < 4; ++r) {
        float p = __expf(sc[c][tt][r] - mx[r]);
        sc[c][tt][r] = p;
        sm[r] += p;
      }
#pragma unroll
  for (int r = 0; r < 4; ++r)
#pragma unroll
    for (int off = 8; off; off >>= 1) sm[r] += __shfl_xor(sm[r], off, 16);
  float inv[4];
#pragma unroll
  for (int r = 0; r < 4; ++r) inv[r] = 1.f / sm[r];
#pragma unroll
  for (int c = 0; c < 5; ++c)
#pragma unroll
    for (int tt = 0; tt < 4; ++tt)
#pragma unroll
      for (int r = 0; r < 4; ++r) sc[c][tt][r] *= inv[r];

  // ---- pass 2: PV ----
  f32x4 o[4];
#pragma unroll
  for (int dt = 0; dt < 4; ++dt) o[dt] = (f32x4){0.f, 0.f, 0.f, 0.f};

  {
    i32x4 vr[2];
#pragma unroll
    for (int i = 0; i < 2; ++i) {
      int rr = srow + i * 32;
      int js = jlo + jel; js = js < 0 ? 0 : (js > 2040 ? 2040 : js);
      vr[i] = *(const i32x4*)(vgbase + 2 * ((size_t)rr * 2048 + js));
    }
    __syncthreads();
#pragma unroll
    for (int i = 0; i < 2; ++i) {
      int rr = srow + i * 32;
      *(i32x4*)(Vs[0] + rr * 128 + (soff ^ ((rr & 7) << 4))) = vr[i];
    }
  }
  __syncthreads();

  char* pw = Ps[wave];
#pragma unroll
  for (int c = 0; c < 5; ++c) {
    int cur = c & 1;
    i32x4 nv[2];
    if (c < 4) {
#pragma unroll
      for (int i = 0; i < 2; ++i) {
        int rr = srow + i * 32;
        int js = jlo + (c + 1) * 64 + jel; js = js < 0 ? 0 : (js > 2040 ? 2040 : js);
        nv[i] = *(const i32x4*)(vgbase + 2 * ((size_t)rr * 2048 + js));
      }
    }
#pragma unroll
    for (int tt = 0; tt < 4; ++tt)
#pragma unroll
      for (int r = 0; r < 4; ++r)
        *(unsigned short*)(pw + (4 * lg + r) * 144 + (tt * 16 + l15) * 2) = f2bf(sc[c][tt][r]);
    short8 pa0 = *(const short8*)(pw + l15 * 144 + lg * 16);
    short8 pa1 = *(const short8*)(pw + l15 * 144 + 64 + lg * 16);
#pragma unroll
    for (int dt = 0; dt < 4; ++dt) {
      int row = dt * 16 + l15;
      short8 v0 = *(const short8*)(Vs[cur] + row * 128 + ((lg * 16) ^ ((row & 7) << 4)));
      short8 v1 = *(const short8*)(Vs[cur] + row * 128 + ((64 + lg * 16) ^ ((row & 7) << 4)));
      o[dt] = __builtin_amdgcn_mfma_f32_16x16x32_bf16(pa0, v0, o[dt], 0, 0, 0);
      o[dt] = __builtin_amdgcn_mfma_f32_16x16x32_bf16(pa1, v1, o[dt], 0, 0, 0);
    }
    if (c < 4) {
      __syncthreads();
#pragma unroll
      for (int i = 0; i < 2; ++i) {
        int rr = srow + i * 32;
        *(i32x4*)(Vs[cur ^ 1] + rr * 128 + (soff ^ ((rr & 7) << 4))) = nv[i];
      }
      __syncthreads();
    }
  }

  char* ob = (char*)out + 2 * ((size_t)(b * L_SEQ + q0 + wave * 16) * D_MODEL + h * 64);
#pragma unroll
  for (int dt = 0; dt < 4; ++dt)
#pragma unroll
    for (int r = 0; r < 4; ++r)
      *(unsigned short*)(ob + 2 * ((size_t)(4 * lg + r) * D_MODEL + dt * 16 + l15)) = f2bf(o[dt][r]);
}

// ---------------- launcher ----------------
extern "C" void kernel_launch(void* const* d_in, const int* in_sizes, int n_in,
                              void* d_out, int out_size, void* d_ws, size_t ws_size,
                              hipStream_t stream) {
  const float* x      = (const float*)d_in[0];
  const float* qkv_w  = (const float*)d_in[1];
  const float* qkv_b  = (const float*)d_in[2];
  const float* out_w  = (const float*)d_in[3];
  const float* out_b  = (const float*)d_in[4];
  const float* ln1_g  = (const float*)d_in[5];
  const float* ln1_b  = (const float*)d_in[6];
  const float* ln2_g  = (const float*)d_in[7];
  const float* ln2_b  = (const float*)d_in[8];
  const float* ffn_w1 = (const float*)d_in[9];
  const float* ffn_b1 = (const float*)d_in[10];
  const float* ffn_w2 = (const float*)d_in[11];
  const float* ffn_b2 = (const float*)d_in[12];
  float* out = (float*)d_out;
  (void)in_sizes; (void)n_in; (void)out_size; (void)ws_size;

  char* ws = (char*)d_ws;
  size_t off = 0;
  auto alloc = [&](size_t bytes) {
    char* p = ws + off;
    off += (bytes + 255) & ~(size_t)255;
    return p;
  };
  __hip_bfloat16* hbuf    = (__hip_bfloat16*)alloc((size_t)NROWS * 1024 * 2);
  __hip_bfloat16* qkvbuf  = (__hip_bfloat16*)alloc((size_t)NROWS * 3072 * 2);
  __hip_bfloat16* attnbuf = (__hip_bfloat16*)alloc((size_t)NROWS * 1024 * 2);
  float*          x2buf   = (float*)alloc((size_t)NROWS * 1024 * 4);
  __hip_bfloat16* wqkvT   = (__hip_bfloat16*)alloc((size_t)3072 * 1024 * 2);
  __hip_bfloat16* woutT   = (__hip_bfloat16*)alloc((size_t)1024 * 1024 * 2);
  __hip_bfloat16* wf1T    = (__hip_bfloat16*)alloc((size_t)2048 * 1024 * 2);
  __hip_bfloat16* wf2T    = (__hip_bfloat16*)alloc((size_t)1024 * 2048 * 2);
  __hip_bfloat16* vTbuf   = (__hip_bfloat16*)alloc((size_t)32 * 64 * 2048 * 2);
  __hip_bfloat16* gbuf    = qkvbuf;   // reuse: qkv dead after attention

  // allow 128 KB dynamic LDS for the 256-tile GEMMs (idempotent, capture-safe)
  hipFuncSetAttribute((const void*)gemm256_kernel<0>, hipFuncAttributeMaxDynamicSharedMemorySize, 131072);
  hipFuncSetAttribute((const void*)gemm256_kernel<1>, hipFuncAttributeMaxDynamicSharedMemorySize, 131072);

  dim3 blk(256);
  prep_kernel<<<8192 + NROWS, blk, 0, stream>>>(qkv_w, wqkvT, out_w, woutT,
                                                ffn_w1, wf1T, ffn_w2, wf2T,
                                                x, ln1_g, ln1_b, hbuf);
  gemm256_kernel<0><<<dim3(3072 / 256, NROWS / 256), 512, 131072, stream>>>(hbuf, wqkvT, qkv_b, qkvbuf, NROWS, 3072, 1024);
  vtrans_kernel<<<dim3(L_SEQ / 64, BATCH * N_HEADS), blk, 0, stream>>>(qkvbuf, vTbuf);
  attn_mfma_kernel<<<dim3(L_SEQ / 64, BATCH * N_HEADS), blk, 0, stream>>>(qkvbuf, vTbuf, attnbuf);
  gemm_kernel<2><<<dim3(1024 / 128, NROWS / 128), blk, 0, stream>>>(attnbuf, woutT, out_b, x, x2buf, NROWS, 1024, 1024);
  ln_kernel<<<NROWS, blk, 0, stream>>>(x2buf, ln2_g, ln2_b, hbuf);
  gemm256_kernel<1><<<dim3(2048 / 256, NROWS / 256), 512, 131072, stream>>>(hbuf, wf1T, ffn_b1, gbuf, NROWS, 2048, 1024);
  gemm_kernel<2><<<dim3(1024 / 128, NROWS / 128), blk, 0, stream>>>(gbuf, wf2T, ffn_b2, x2buf, out, NROWS, 1024, 2048);
}

// Round 8
// 273.031 us; speedup vs baseline: 1.0293x; 1.0293x over previous
//
#include <hip/hip_runtime.h>
#include <hip/hip_bf16.h>

#define D_MODEL 1024
#define L_SEQ   2048
#define BATCH   2
#define NROWS   (BATCH*L_SEQ)   // 4096
#define N_HEADS 16
#define HD      64
#define WIN     128             // half window

typedef __attribute__((ext_vector_type(8))) short short8;
typedef __attribute__((ext_vector_type(4))) float f32x4;
typedef __attribute__((ext_vector_type(4))) int   i32x4;
typedef __attribute__((ext_vector_type(4))) unsigned short u16x4;

__device__ __forceinline__ float bf2f(unsigned short u) {
  union { unsigned int i; float f; } c;
  c.i = ((unsigned int)u) << 16;
  return c.f;
}
__device__ __forceinline__ unsigned short f2bf(float f) {
  __hip_bfloat16 h = __float2bfloat16(f);
  return *reinterpret_cast<unsigned short*>(&h);
}

// async global->LDS, 16B per lane. LDS dest is wave-uniform base + lane*16.
__device__ __forceinline__ void gload16(const void* g, void* l) {
  __builtin_amdgcn_global_load_lds((const __attribute__((address_space(1))) unsigned int*)g,
                                   (__attribute__((address_space(3))) unsigned int*)l, 16, 0, 0);
}

// ---------------- prep: 4 weight transposes (f32 [K][N] -> bf16 [N][K]) + LN1 ----------------
__device__ __forceinline__ void wtrans_body(const float* __restrict__ W,
                                            __hip_bfloat16* __restrict__ Wt,
                                            int K, int N, int tile_id) {
  __shared__ float tile[32][33];
  int tx = threadIdx.x & 31, ty = threadIdx.x >> 5;   // 32 x 8
  int ntile_n = N >> 5;
  int n0 = (tile_id % ntile_n) * 32, k0 = (tile_id / ntile_n) * 32;
#pragma unroll
  for (int i = 0; i < 4; ++i) {
    int k = k0 + ty + i * 8;
    tile[ty + i * 8][tx] = W[(size_t)k * N + n0 + tx];
  }
  __syncthreads();
#pragma unroll
  for (int i = 0; i < 4; ++i) {
    int n = n0 + ty + i * 8;
    Wt[(size_t)n * K + k0 + tx] = __float2bfloat16(tile[tx][ty + i * 8]);
  }
}

__device__ __forceinline__ void ln_body(const float* __restrict__ x,
                                        const float* __restrict__ g,
                                        const float* __restrict__ beta,
                                        __hip_bfloat16* __restrict__ out, int row) {
  int t = threadIdx.x;
  const float4* xr = (const float4*)(x + (size_t)row * D_MODEL);
  float4 v = xr[t];
  float s  = v.x + v.y + v.z + v.w;
  float sq = v.x * v.x + v.y * v.y + v.z * v.z + v.w * v.w;
#pragma unroll
  for (int off = 32; off; off >>= 1) {
    s  += __shfl_xor(s, off);
    sq += __shfl_xor(sq, off);
  }
  __shared__ float red[8];
  int w = t >> 6;
  if ((t & 63) == 0) { red[w] = s; red[4 + w] = sq; }
  __syncthreads();
  s  = red[0] + red[1] + red[2] + red[3];
  sq = red[4] + red[5] + red[6] + red[7];
  float mean = s * (1.0f / 1024.0f);
  float var  = sq * (1.0f / 1024.0f) - mean * mean;
  float rs   = rsqrtf(var + 1e-5f);
  float4 gv = ((const float4*)g)[t];
  float4 bv = ((const float4*)beta)[t];
  u16x4 o;
  o.x = f2bf((v.x - mean) * rs * gv.x + bv.x);
  o.y = f2bf((v.y - mean) * rs * gv.y + bv.y);
  o.z = f2bf((v.z - mean) * rs * gv.z + bv.z);
  o.w = f2bf((v.w - mean) * rs * gv.w + bv.w);
  ((u16x4*)(out + (size_t)row * D_MODEL))[t] = o;
}

__global__ __launch_bounds__(256) void prep_kernel(
    const float* __restrict__ qkv_w, __hip_bfloat16* __restrict__ wqkvT,
    const float* __restrict__ out_w, __hip_bfloat16* __restrict__ woutT,
    const float* __restrict__ ffn_w1, __hip_bfloat16* __restrict__ wf1T,
    const float* __restrict__ ffn_w2, __hip_bfloat16* __restrict__ wf2T,
    const float* __restrict__ x, const float* __restrict__ ln1_g,
    const float* __restrict__ ln1_b, __hip_bfloat16* __restrict__ hbuf) {
  int id = blockIdx.x;
  if (id < 3072)      wtrans_body(qkv_w,  wqkvT, 1024, 3072, id);
  else if (id < 4096) wtrans_body(out_w,  woutT, 1024, 1024, id - 3072);
  else if (id < 6144) wtrans_body(ffn_w1, wf1T,  1024, 2048, id - 4096);
  else if (id < 8192) wtrans_body(ffn_w2, wf2T,  2048, 1024, id - 6144);
  else                ln_body(x, ln1_g, ln1_b, hbuf, id - 8192);
}

// ---------------- standalone layernorm (for LN2) ----------------
__global__ __launch_bounds__(256) void ln_kernel(const float* __restrict__ x,
                                                 const float* __restrict__ g,
                                                 const float* __restrict__ beta,
                                                 __hip_bfloat16* __restrict__ out) {
  ln_body(x, g, beta, out, blockIdx.x);
}

// ---------------- V transpose: qkv V part -> vT[bh][d][j] bf16 ----------------
__global__ __launch_bounds__(256) void vtrans_kernel(const __hip_bfloat16* __restrict__ qkv,
                                                     __hip_bfloat16* __restrict__ vT) {
  __shared__ unsigned short tile[64][72];
  int bh = blockIdx.y, b = bh >> 4, h = bh & 15;
  int j0 = blockIdx.x * 64;
  int t = threadIdx.x;
#pragma unroll
  for (int i = 0; i < 2; ++i) {
    int c = t + i * 256;            // 0..511
    int row = c >> 3, off = c & 7;  // row 0..63, 16B chunk
    *(i32x4*)&tile[row][off * 8] =
        *(const i32x4*)&qkv[(size_t)(b * L_SEQ + j0 + row) * 3072 + 2 * D_MODEL + h * 64 + off * 8];
  }
  __syncthreads();
#pragma unroll
  for (int i = 0; i < 2; ++i) {
    int c = t + i * 256;
    int d = c >> 3, off = c & 7;    // d 0..63, j chunk
    short8 o;
#pragma unroll
    for (int e = 0; e < 8; ++e) o[e] = (short)tile[off * 8 + e][d];
    *(short8*)&vT[((size_t)bh * 64 + d) * 2048 + j0 + off * 8] = o;
  }
}

// ---------------- 128x128 MFMA GEMM: counted-vmcnt 2-phase dbuf (T4) ----------------
// Per wave each STAGE = exactly 8 global_load_lds. Schedule per K-step:
//   STAGE(next) ; s_waitcnt vmcnt(8)  <- current tile resident, next 8 stay IN FLIGHT
//   s_barrier ; sched_barrier ; ds_read+MFMA ; s_barrier
// Never drains vmcnt to 0 in the main loop (T4; m218 counted-vs-drain0 +38%).
// LDS content XOR-swizzled via pre-swizzled global source (rule #21 both-sides).
// MODE 0: bias -> bf16 ; MODE 1: gelu(bias+acc) -> bf16 ; MODE 2: bias+acc+resid -> f32
template <int MODE>
__global__ __launch_bounds__(256) void gemm_kernel(const __hip_bfloat16* __restrict__ A,
                                                   const __hip_bfloat16* __restrict__ Bt,
                                                   const float* __restrict__ bias,
                                                   const float* __restrict__ resid,
                                                   void* __restrict__ outp,
                                                   int M, int N, int K) {
  (void)M;
  __shared__ __align__(16) char lsA[2][128 * 128];
  __shared__ __align__(16) char lsB[2][128 * 128];

  int tid  = threadIdx.x;
  int lane = tid & 63;
  int wave = tid >> 6;
  int wr = wave >> 1, wc = wave & 1;
  int l15 = lane & 15, lg = lane >> 4;

  // XCD-chunked bijective swizzle (all grids are multiples of 8)
  int gx = gridDim.x;
  int nwg = gx * gridDim.y;
  int flat = blockIdx.y * gx + blockIdx.x;
  int cpx = nwg >> 3;
  int sw = (flat & 7) * cpx + (flat >> 3);
  int m0 = (sw / gx) * 128;
  int n0 = (sw % gx) * 128;

  const char* Abase = (const char*)A;
  const char* Bbase = (const char*)Bt;
  size_t strideK = (size_t)K * 2;
  int KT = K >> 6;

  int srow_in  = lane >> 3;                        // 0..7 == row&7
  int scb_src  = (((lane & 7) ^ srow_in)) * 16;    // pre-swizzled global byte col

  auto STAGE = [&](int buf, int kt) {
    size_t kb = (size_t)kt * 128;
#pragma unroll
    for (int i = 0; i < 4; ++i) {
      int chunk = wave * 4 + i;            // 0..15, wave-uniform
      int row = chunk * 8 + srow_in;       // 0..127
      gload16(Abase + (size_t)(m0 + row) * strideK + kb + scb_src, lsA[buf] + chunk * 1024);
      gload16(Bbase + (size_t)(n0 + row) * strideK + kb + scb_src, lsB[buf] + chunk * 1024);
    }
  };

  f32x4 acc[4][4];
#pragma unroll
  for (int i = 0; i < 4; ++i)
#pragma unroll
    for (int j = 0; j < 4; ++j) acc[i][j] = (f32x4){0.f, 0.f, 0.f, 0.f};

  STAGE(0, 0);

  for (int kt = 0; kt < KT; ++kt) {
    int cur = kt & 1;
    if (kt + 1 < KT) {
      STAGE(cur ^ 1, kt + 1);                          // issue next tile: stays in flight
      asm volatile("s_waitcnt vmcnt(8)" ::: "memory"); // oldest 8 (tile kt) complete
    } else {
      asm volatile("s_waitcnt vmcnt(0)" ::: "memory"); // last tile: full drain
    }
    __builtin_amdgcn_s_barrier();          // all waves: tile kt visible in LDS
    __builtin_amdgcn_sched_barrier(0);     // no ds_read hoisting above the barrier
#pragma unroll
    for (int ks = 0; ks < 2; ++ks) {
      short8 af[4], bfr[4];
#pragma unroll
      for (int mi = 0; mi < 4; ++mi) {
        int row = wr * 64 + mi * 16 + l15;
        af[mi] = *(const short8*)(lsA[cur] + row * 128 + ((ks * 64 + lg * 16) ^ ((row & 7) << 4)));
      }
#pragma unroll
      for (int ni = 0; ni < 4; ++ni) {
        int row = wc * 64 + ni * 16 + l15;
        bfr[ni] = *(const short8*)(lsB[cur] + row * 128 + ((ks * 64 + lg * 16) ^ ((row & 7) << 4)));
      }
#pragma unroll
      for (int mi = 0; mi < 4; ++mi)
#pragma unroll
        for (int ni = 0; ni < 4; ++ni)
          acc[mi][ni] = __builtin_amdgcn_mfma_f32_16x16x32_bf16(af[mi], bfr[ni], acc[mi][ni], 0, 0, 0);
    }
    __builtin_amdgcn_sched_barrier(0);
    __builtin_amdgcn_s_barrier();          // readers of buf cur done -> next iter may overwrite
  }

  // epilogue: D row = 4*(lane>>4)+r, col = lane&15
  int colg = n0 + wc * 64;
  int rowg = m0 + wr * 64;
#pragma unroll
  for (int mi = 0; mi < 4; ++mi) {
#pragma unroll
    for (int ni = 0; ni < 4; ++ni) {
      int col = colg + ni * 16 + l15;
      float bs = bias[col];
#pragma unroll
      for (int r = 0; r < 4; ++r) {
        int row = rowg + mi * 16 + (lg << 2) + r;
        float v = acc[mi][ni][r] + bs;
        if (MODE == 1) v = 0.5f * v * (1.0f + erff(v * 0.70710678118654752f));
        if (MODE == 2) {
          ((float*)outp)[(size_t)row * N + col] = v + resid[(size_t)row * N + col];
        } else {
          ((__hip_bfloat16*)outp)[(size_t)row * N + col] = __float2bfloat16(v);
        }
      }
    }
  }
}

// ---------------- MFMA windowed attention ----------------
// Block: 64 q-rows of one (b,h); 4 waves x 16 q-rows. 5 key chunks of 64 (=320 keys).
__global__ __launch_bounds__(256) void attn_mfma_kernel(const __hip_bfloat16* __restrict__ qkv,
                                                        const __hip_bfloat16* __restrict__ vT,
                                                        __hip_bfloat16* __restrict__ out) {
  __shared__ char Ks[2][8192];   // 64 keys x 128B (swizzled)
  __shared__ char Vs[2][8192];   // 64 d    x 128B of j (swizzled)
  __shared__ char Ps[4][2304];   // per-wave P chunk: 16 x 72 bf16

  const int t = threadIdx.x;
  const int lane = t & 63;
  const int wave = t >> 6;
  const int l15 = lane & 15;
  const int lg  = lane >> 4;
  const int bh = blockIdx.y, b = bh >> 4, h = bh & 15;
  const int q0 = blockIdx.x * 64;
  const int jlo = q0 - 128;

  short8 qf0, qf1;
  {
    int qrow = q0 + wave * 16 + l15;
    const char* qp = (const char*)qkv + 2 * ((size_t)(b * L_SEQ + qrow) * 3072 + h * 64 + 8 * lg);
    qf0 = *(const short8*)qp;
    qf1 = *(const short8*)(qp + 64);
  }

  const int srow = t >> 3;           // 0..31 (two rows per thread: srow, srow+32)
  const int soff = (t & 7) * 16;     // byte chunk in 128B row
  const int jel  = (t & 7) * 8;      // element offset (j)

  const char* kgbase = (const char*)qkv + 2 * ((size_t)b * L_SEQ * 3072 + D_MODEL + h * 64);
  const char* vgbase = (const char*)vT + 2 * ((size_t)bh * 64 * 2048);

  f32x4 sc[5][4];
#pragma unroll
  for (int c = 0; c < 5; ++c)
#pragma unroll
    for (int tt = 0; tt < 4; ++tt) sc[c][tt] = (f32x4){0.f, 0.f, 0.f, 0.f};

  // ---- pass 1: QK^T ----
  {
    i32x4 kr[2];
#pragma unroll
    for (int i = 0; i < 2; ++i) {
      int rr = srow + i * 32;
      int tok = jlo + rr; tok = tok < 0 ? 0 : (tok > 2047 ? 2047 : tok);
      kr[i] = *(const i32x4*)(kgbase + (size_t)tok * 6144 + soff);
    }
#pragma unroll
    for (int i = 0; i < 2; ++i) {
      int rr = srow + i * 32;
      *(i32x4*)(Ks[0] + rr * 128 + (soff ^ ((rr & 7) << 4))) = kr[i];
    }
  }
  __syncthreads();

#pragma unroll
  for (int c = 0; c < 5; ++c) {
    int cur = c & 1;
    i32x4 nk[2];
    if (c < 4) {
#pragma unroll
      for (int i = 0; i < 2; ++i) {
        int rr = srow + i * 32;
        int tok = jlo + (c + 1) * 64 + rr; tok = tok < 0 ? 0 : (tok > 2047 ? 2047 : tok);
        nk[i] = *(const i32x4*)(kgbase + (size_t)tok * 6144 + soff);
      }
    }
#pragma unroll
    for (int tt = 0; tt < 4; ++tt) {
      int row = tt * 16 + l15;
      short8 k0 = *(const short8*)(Ks[cur] + row * 128 + ((lg * 16) ^ ((row & 7) << 4)));
      short8 k1 = *(const short8*)(Ks[cur] + row * 128 + ((64 + lg * 16) ^ ((row & 7) << 4)));
      sc[c][tt] = __builtin_amdgcn_mfma_f32_16x16x32_bf16(qf0, k0, sc[c][tt], 0, 0, 0);
      sc[c][tt] = __builtin_amdgcn_mfma_f32_16x16x32_bf16(qf1, k1, sc[c][tt], 0, 0, 0);
    }
    if (c < 4) {
      __syncthreads();
#pragma unroll
      for (int i = 0; i < 2; ++i) {
        int rr = srow + i * 32;
        *(i32x4*)(Ks[cur ^ 1] + rr * 128 + (soff ^ ((rr & 7) << 4))) = nk[i];
      }
      __syncthreads();
    }
  }

  // ---- mask + softmax ----
  const int iqb = q0 + wave * 16 + 4 * lg;
  const int kgb = jlo + l15;
#pragma unroll
  for (int c = 0; c < 5; ++c)
#pragma unroll
    for (int tt = 0; tt < 4; ++tt) {
      int kg = kgb + c * 64 + tt * 16;
#pragma unroll
      for (int r = 0; r < 4; ++r) {
        int iq = iqb + r;
        bool ok = (kg >= 0) && (kg < L_SEQ) && (kg >= iq - WIN) && (kg <= iq + WIN);
        sc[c][tt][r] = ok ? sc[c][tt][r] * 0.125f : -1e30f;
      }
    }
  float mx[4] = {-1e30f, -1e30f, -1e30f, -1e30f};
#pragma unroll
  for (int c = 0; c < 5; ++c)
#pragma unroll
    for (int tt = 0; tt < 4; ++tt)
#pragma unroll
      for (int r = 0; r < 4; ++r) mx[r] = fmaxf(mx[r], sc[c][tt][r]);
#pragma unroll
  for (int r = 0; r < 4; ++r)
#pragma unroll
    for (int off = 8; off; off >>= 1) mx[r] = fmaxf(mx[r], __shfl_xor(mx[r], off, 16));
  float sm[4] = {0.f, 0.f, 0.f, 0.f};
#pragma unroll
  for (int c = 0; c < 5; ++c)
#pragma unroll
    for (int tt = 0; tt < 4; ++tt)
#pragma unroll
      for (int r = 0; r < 4; ++r) {
        float p = __expf(sc[c][tt][r] - mx[r]);
        sc[c][tt][r] = p;
        sm[r] += p;
      }
#pragma unroll
  for (int r = 0; r < 4; ++r)
#pragma unroll
    for (int off = 8; off; off >>= 1) sm[r] += __shfl_xor(sm[r], off, 16);
  float inv[4];
#pragma unroll
  for (int r = 0; r < 4; ++r) inv[r] = 1.f / sm[r];
#pragma unroll
  for (int c = 0; c < 5; ++c)
#pragma unroll
    for (int tt = 0; tt < 4; ++tt)
#pragma unroll
      for (int r = 0; r < 4; ++r) sc[c][tt][r] *= inv[r];

  // ---- pass 2: PV ----
  f32x4 o[4];
#pragma unroll
  for (int dt = 0; dt < 4; ++dt) o[dt] = (f32x4){0.f, 0.f, 0.f, 0.f};

  {
    i32x4 vr[2];
#pragma unroll
    for (int i = 0; i < 2; ++i) {
      int rr = srow + i * 32;
      int js = jlo + jel; js = js < 0 ? 0 : (js > 2040 ? 2040 : js);
      vr[i] = *(const i32x4*)(vgbase + 2 * ((size_t)rr * 2048 + js));
    }
    __syncthreads();
#pragma unroll
    for (int i = 0; i < 2; ++i) {
      int rr = srow + i * 32;
      *(i32x4*)(Vs[0] + rr * 128 + (soff ^ ((rr & 7) << 4))) = vr[i];
    }
  }
  __syncthreads();

  char* pw = Ps[wave];
#pragma unroll
  for (int c = 0; c < 5; ++c) {
    int cur = c & 1;
    i32x4 nv[2];
    if (c < 4) {
#pragma unroll
      for (int i = 0; i < 2; ++i) {
        int rr = srow + i * 32;
        int js = jlo + (c + 1) * 64 + jel; js = js < 0 ? 0 : (js > 2040 ? 2040 : js);
        nv[i] = *(const i32x4*)(vgbase + 2 * ((size_t)rr * 2048 + js));
      }
    }
#pragma unroll
    for (int tt = 0; tt < 4; ++tt)
#pragma unroll
      for (int r = 0; r < 4; ++r)
        *(unsigned short*)(pw + (4 * lg + r) * 144 + (tt * 16 + l15) * 2) = f2bf(sc[c][tt][r]);
    short8 pa0 = *(const short8*)(pw + l15 * 144 + lg * 16);
    short8 pa1 = *(const short8*)(pw + l15 * 144 + 64 + lg * 16);
#pragma unroll
    for (int dt = 0; dt < 4; ++dt) {
      int row = dt * 16 + l15;
      short8 v0 = *(const short8*)(Vs[cur] + row * 128 + ((lg * 16) ^ ((row & 7) << 4)));
      short8 v1 = *(const short8*)(Vs[cur] + row * 128 + ((64 + lg * 16) ^ ((row & 7) << 4)));
      o[dt] = __builtin_amdgcn_mfma_f32_16x16x32_bf16(pa0, v0, o[dt], 0, 0, 0);
      o[dt] = __builtin_amdgcn_mfma_f32_16x16x32_bf16(pa1, v1, o[dt], 0, 0, 0);
    }
    if (c < 4) {
      __syncthreads();
#pragma unroll
      for (int i = 0; i < 2; ++i) {
        int rr = srow + i * 32;
        *(i32x4*)(Vs[cur ^ 1] + rr * 128 + (soff ^ ((rr & 7) << 4))) = nv[i];
      }
      __syncthreads();
    }
  }

  char* ob = (char*)out + 2 * ((size_t)(b * L_SEQ + q0 + wave * 16) * D_MODEL + h * 64);
#pragma unroll
  for (int dt = 0; dt < 4; ++dt)
#pragma unroll
    for (int r = 0; r < 4; ++r)
      *(unsigned short*)(ob + 2 * ((size_t)(4 * lg + r) * D_MODEL + dt * 16 + l15)) = f2bf(o[dt][r]);
}

// ---------------- launcher ----------------
extern "C" void kernel_launch(void* const* d_in, const int* in_sizes, int n_in,
                              void* d_out, int out_size, void* d_ws, size_t ws_size,
                              hipStream_t stream) {
  const float* x      = (const float*)d_in[0];
  const float* qkv_w  = (const float*)d_in[1];
  const float* qkv_b  = (const float*)d_in[2];
  const float* out_w  = (const float*)d_in[3];
  const float* out_b  = (const float*)d_in[4];
  const float* ln1_g  = (const float*)d_in[5];
  const float* ln1_b  = (const float*)d_in[6];
  const float* ln2_g  = (const float*)d_in[7];
  const float* ln2_b  = (const float*)d_in[8];
  const float* ffn_w1 = (const float*)d_in[9];
  const float* ffn_b1 = (const float*)d_in[10];
  const float* ffn_w2 = (const float*)d_in[11];
  const float* ffn_b2 = (const float*)d_in[12];
  float* out = (float*)d_out;
  (void)in_sizes; (void)n_in; (void)out_size; (void)ws_size;

  char* ws = (char*)d_ws;
  size_t off = 0;
  auto alloc = [&](size_t bytes) {
    char* p = ws + off;
    off += (bytes + 255) & ~(size_t)255;
    return p;
  };
  __hip_bfloat16* hbuf    = (__hip_bfloat16*)alloc((size_t)NROWS * 1024 * 2);
  __hip_bfloat16* qkvbuf  = (__hip_bfloat16*)alloc((size_t)NROWS * 3072 * 2);
  __hip_bfloat16* attnbuf = (__hip_bfloat16*)alloc((size_t)NROWS * 1024 * 2);
  float*          x2buf   = (float*)alloc((size_t)NROWS * 1024 * 4);
  __hip_bfloat16* wqkvT   = (__hip_bfloat16*)alloc((size_t)3072 * 1024 * 2);
  __hip_bfloat16* woutT   = (__hip_bfloat16*)alloc((size_t)1024 * 1024 * 2);
  __hip_bfloat16* wf1T    = (__hip_bfloat16*)alloc((size_t)2048 * 1024 * 2);
  __hip_bfloat16* wf2T    = (__hip_bfloat16*)alloc((size_t)1024 * 2048 * 2);
  __hip_bfloat16* vTbuf   = (__hip_bfloat16*)alloc((size_t)32 * 64 * 2048 * 2);
  __hip_bfloat16* gbuf    = qkvbuf;   // reuse: qkv dead after attention

  dim3 blk(256);
  prep_kernel<<<8192 + NROWS, blk, 0, stream>>>(qkv_w, wqkvT, out_w, woutT,
                                                ffn_w1, wf1T, ffn_w2, wf2T,
                                                x, ln1_g, ln1_b, hbuf);
  gemm_kernel<0><<<dim3(3072 / 128, NROWS / 128), blk, 0, stream>>>(hbuf, wqkvT, qkv_b, nullptr, qkvbuf, NROWS, 3072, 1024);
  vtrans_kernel<<<dim3(L_SEQ / 64, BATCH * N_HEADS), blk, 0, stream>>>(qkvbuf, vTbuf);
  attn_mfma_kernel<<<dim3(L_SEQ / 64, BATCH * N_HEADS), blk, 0, stream>>>(qkvbuf, vTbuf, attnbuf);
  gemm_kernel<2><<<dim3(1024 / 128, NROWS / 128), blk, 0, stream>>>(attnbuf, woutT, out_b, x, x2buf, NROWS, 1024, 1024);
  ln_kernel<<<NROWS, blk, 0, stream>>>(x2buf, ln2_g, ln2_b, hbuf);
  gemm_kernel<1><<<dim3(2048 / 128, NROWS / 128), blk, 0, stream>>>(hbuf, wf1T, ffn_b1, nullptr, gbuf, NROWS, 2048, 1024);
  gemm_kernel<2><<<dim3(1024 / 128, NROWS / 128), blk, 0, stream>>>(gbuf, wf2T, ffn_b2, x2buf, out, NROWS, 1024, 2048);
}